// Round 6
// baseline (1241.369 us; speedup 1.0000x reference)
//
#include <hip/hip_runtime.h>
#include <hip/hip_fp16.h>

#define BB 2048
#define NN 1568
#define CD 48
#define TPB 512
#define WSLOTS 98304   // 3 c * 4 g * 16 d * 512 ts uint4 slots (1.5 MB in d_ws)

typedef _Float16 h2v __attribute__((ext_vector_type(2)));

// ---- scalar-safe half2 helpers (no local-array casts)
__device__ __forceinline__ unsigned packh2(float a, float b) {
    __half2 h = __floats2half2_rn(a, b);
    unsigned r; __builtin_memcpy(&r, &h, 4); return r;
}
__device__ __forceinline__ float2 uph2(unsigned v) {
    __half2 h; __builtin_memcpy(&h, &v, 4); return __half22float2(h);
}
// f32 += h2 . h2  (v_dot2_f32_f16)
__device__ __forceinline__ float fdot2u(unsigned a, unsigned b, float c) {
#if __has_builtin(__builtin_amdgcn_fdot2)
    h2v av, bv;
    __builtin_memcpy(&av, &a, 4); __builtin_memcpy(&bv, &b, 4);
    return __builtin_amdgcn_fdot2(av, bv, c, false);
#else
    const float2 fa = uph2(a), fb = uph2(b);
    return c + fa.x * fb.x + fa.y * fb.y;
#endif
}
__device__ __forceinline__ unsigned hadd2u(unsigned a, unsigned b) {
    __half2 ha, hb; __builtin_memcpy(&ha, &a, 4); __builtin_memcpy(&hb, &b, 4);
    __half2 r = __hadd2(ha, hb);
    unsigned q; __builtin_memcpy(&q, &r, 4); return q;
}
__device__ __forceinline__ unsigned hfma2u(unsigned a, unsigned b, unsigned c) {
    __half2 ha, hb, hc;
    __builtin_memcpy(&ha, &a, 4); __builtin_memcpy(&hb, &b, 4); __builtin_memcpy(&hc, &c, 4);
    __half2 r = __hfma2(ha, hb, hc);
    unsigned q; __builtin_memcpy(&q, &r, 4); return q;
}

// =================== K0: W fp32 -> fp16, swizzled ===================
// Wh slot layout: [ (c*4+g)*16 + d ][ ts ]  (uint4 = 8 fp16 = all e of one d),
// covering n = g*512 + ts. Fused-kernel wave loads are fully coalesced.
__global__ __launch_bounds__(256)
void wcast(const float* __restrict__ W, uint4* __restrict__ Wh)
{
    const int id = blockIdx.x * 256 + threadIdx.x;   // 0..24575
    const int ts = id & 511;
    const int r  = id >> 9;        // 0..47
    const int dq = r & 3;          // d quad (4 d per thread)
    const int ci = r >> 2;         // c*4+g, 0..11
    const int g  = ci & 3;
    const int c  = ci >> 2;
    const int n  = g * 512 + ts;
    uint4* dst = Wh + (size_t)ci * 8192 + dq * 4 * 512 + ts;
    if (n < NN) {
        const float* src = W + ((size_t)(c * NN + n)) * 128 + dq * 32;
#pragma unroll
        for (int dd = 0; dd < 4; ++dd) {
            const float4 f0 = *(const float4*)(src + dd * 8);
            const float4 f1 = *(const float4*)(src + dd * 8 + 4);
            uint4 q;
            q.x = packh2(f0.x, f0.y); q.y = packh2(f0.z, f0.w);
            q.z = packh2(f1.x, f1.y); q.w = packh2(f1.z, f1.w);
            dst[dd * 512] = q;
        }
    } else {
        const uint4 z = make_uint4(0u, 0u, 0u, 0u);
#pragma unroll
        for (int dd = 0; dd < 4; ++dd) dst[dd * 512] = z;
    }
}

// =================== K1: fully fused, u entirely in REGISTERS ===================
// TPB=512 (allocator-friendly: r1 got 104 VGPRs here vs the hard 64-pin at
// TPB=1024 across r3/r4/r5). No __launch_bounds__ — its flat-work-group-size
// min of 1 invalidates waves_per_eu. Instead pin both ends explicitly:
// flat(512,512) makes waves_per_eu(2,2) satisfiable -> VGPR budget 512/2=256,
// comfortably above the ~150-reg peak (uA..uD 96 + wr 32 + x/temps).
// Thread t owns rows t, 512+t, 1024+t (all) and 1536+t (t<32).
__global__ __attribute__((amdgpu_flat_work_group_size(TPB, TPB), amdgpu_waves_per_eu(2, 2)))
void fused(const float* __restrict__ x, const uint4* __restrict__ Wh,
           float* __restrict__ out)
{
    __shared__ float red[8][CD];         // 1,536 B
    __shared__ float vsh[CD];            //   192 B
    __shared__ unsigned vsh2[24];        //    96 B

    const int t = threadIdx.x;
    const int w = t >> 6;
    const int b = blockIdx.x;
    const float* xb = x + (size_t)b * NN * 8;
    const bool hasD = (t < (NN - 1536));     // t < 32

    // issue all x loads up front
    const float4 xa0 = __ldg((const float4*)(xb + (size_t)t * 8));
    const float4 xc0 = __ldg((const float4*)(xb + (size_t)t * 8 + 4));
    const float4 xa1 = __ldg((const float4*)(xb + (size_t)(512 + t) * 8));
    const float4 xc1 = __ldg((const float4*)(xb + (size_t)(512 + t) * 8 + 4));
    const float4 xa2 = __ldg((const float4*)(xb + (size_t)(1024 + t) * 8));
    const float4 xc2 = __ldg((const float4*)(xb + (size_t)(1024 + t) * 8 + 4));
    float4 xa3 = make_float4(0.f, 0.f, 0.f, 0.f), xc3 = xa3;
    if (hasD) {
        xa3 = __ldg((const float4*)(xb + (size_t)(1536 + t) * 8));
        xc3 = __ldg((const float4*)(xb + (size_t)(1536 + t) * 8 + 4));
    }

    unsigned uA[24], uB[24], uC[24], uD[24];
#pragma unroll
    for (int j = 0; j < 24; ++j) uD[j] = 0u;

    // ---------------- phase A: u = W.x -> registers ----------------
    // C3/GG literals -> static indexing everywhere (no scratch).
#define DO_C(C3, UR, GG, XH0, XH1, XH2, XH3) { \
    const uint4* wp = Wh + (size_t)(((C3) * 4 + (GG))) * 8192 + t; \
    _Pragma("unroll") \
    for (int dh = 0; dh < 2; ++dh) { \
        uint4 wr[8]; \
        _Pragma("unroll") \
        for (int d = 0; d < 8; ++d) wr[d] = wp[(dh * 8 + d) * 512]; \
        _Pragma("unroll") \
        for (int k = 0; k < 4; ++k) { \
            const float ua = fdot2u(wr[2*k].x,   XH0, fdot2u(wr[2*k].y,   XH1, \
                             fdot2u(wr[2*k].z,   XH2, fdot2u(wr[2*k].w,   XH3, 0.f)))); \
            const float ub = fdot2u(wr[2*k+1].x, XH0, fdot2u(wr[2*k+1].y, XH1, \
                             fdot2u(wr[2*k+1].z, XH2, fdot2u(wr[2*k+1].w, XH3, 0.f)))); \
            UR[(C3) * 8 + dh * 4 + k] = packh2(ua, ub); \
        } \
    } }

#define DO_ROW(UR, GG, XA, XC) { \
    const unsigned xh0 = packh2(XA.x, XA.y); \
    const unsigned xh1 = packh2(XA.z, XA.w); \
    const unsigned xh2 = packh2(XC.x, XC.y); \
    const unsigned xh3 = packh2(XC.z, XC.w); \
    DO_C(0, UR, GG, xh0, xh1, xh2, xh3) \
    DO_C(1, UR, GG, xh0, xh1, xh2, xh3) \
    DO_C(2, UR, GG, xh0, xh1, xh2, xh3) }

    DO_ROW(uA, 0, xa0, xc0)
    DO_ROW(uB, 1, xa1, xc1)
    DO_ROW(uC, 2, xa2, xc2)
    if (hasD) { DO_ROW(uD, 3, xa3, xc3) }
#undef DO_ROW
#undef DO_C

    // streaming reduce: one half2 pair live at a time (2 floats + shuffles)
#define REDUCE_H2(EXPR) { \
    _Pragma("unroll") \
    for (int j = 0; j < 24; ++j) { \
        float2 g_ = uph2(EXPR); \
        g_.x += __shfl_xor(g_.x, 1);  g_.y += __shfl_xor(g_.y, 1); \
        g_.x += __shfl_xor(g_.x, 2);  g_.y += __shfl_xor(g_.y, 2); \
        g_.x += __shfl_xor(g_.x, 4);  g_.y += __shfl_xor(g_.y, 4); \
        g_.x += __shfl_xor(g_.x, 8);  g_.y += __shfl_xor(g_.y, 8); \
        g_.x += __shfl_xor(g_.x, 16); g_.y += __shfl_xor(g_.y, 16); \
        g_.x += __shfl_xor(g_.x, 32); g_.y += __shfl_xor(g_.y, 32); \
        if ((t & 63) == 0) { red[w][2*j] = g_.x; red[w][2*j+1] = g_.y; } \
    } }

#define SUM8(T) (red[0][T]+red[1][T]+red[2][T]+red[3][T]+red[4][T]+red[5][T] \
                +red[6][T]+red[7][T])

    REDUCE_H2(hadd2u(hadd2u(uA[j], uB[j]), hadd2u(uC[j], uD[j])))
    __syncthreads();
    if (t < CD) {
        const float s = SUM8(t) * (1.0f / 3.0f);
        float q = s * s;
        q += __shfl_xor(q, 1); q += __shfl_xor(q, 2); q += __shfl_xor(q, 4); q += __shfl_xor(q, 8);
        vsh[t] = s * sqrtf(q) / (1.f + q);       // v1
    }
    __syncthreads();
    if (t < 24) vsh2[t] = packh2(vsh[2*t], vsh[2*t+1]);
    __syncthreads();

    // ---------------- passes 1,2: pure-register routing ----------------
#define PASS_ROW(UR) { \
    float l0 = 0.f, l1 = 0.f, l2 = 0.f; \
    _Pragma("unroll") \
    for (int j = 0; j < 8; ++j) { \
        l0 = fdot2u(UR[j],      wv2[j],      l0); \
        l1 = fdot2u(UR[8 + j],  wv2[8 + j],  l1); \
        l2 = fdot2u(UR[16 + j], wv2[16 + j], l2); \
    } \
    const float e0 = __expf(l0), e1 = __expf(l1), e2 = __expf(l2); \
    const float inv = 1.f / (e0 + e1 + e2); \
    const unsigned c0h = packh2(e0 * inv, e0 * inv); \
    const unsigned c1h = packh2(e1 * inv, e1 * inv); \
    const unsigned c2h = packh2(e2 * inv, e2 * inv); \
    _Pragma("unroll") \
    for (int j = 0; j < 8; ++j) { \
        a2[j]      = hfma2u(c0h, UR[j],      a2[j]); \
        a2[8 + j]  = hfma2u(c1h, UR[8 + j],  a2[8 + j]); \
        a2[16 + j] = hfma2u(c2h, UR[16 + j], a2[16 + j]); \
    } }

#pragma unroll 1
    for (int pass = 1; pass <= 2; ++pass) {
        unsigned wv2[24];
#pragma unroll
        for (int j = 0; j < 24; ++j) wv2[j] = vsh2[j];
        unsigned a2[24];
#pragma unroll
        for (int j = 0; j < 24; ++j) a2[j] = 0u;

        PASS_ROW(uA)
        PASS_ROW(uB)
        PASS_ROW(uC)
        if (hasD) { PASS_ROW(uD) }

        REDUCE_H2(a2[j])
        __syncthreads();
        if (t < CD) {
            const float s = SUM8(t);
            float q = s * s;
            q += __shfl_xor(q, 1); q += __shfl_xor(q, 2); q += __shfl_xor(q, 4); q += __shfl_xor(q, 8);
            const float v = s * sqrtf(q) / (1.f + q);
            if (pass == 1) vsh[t] += v;                       // w2 = v1 + v2
            else           out[(size_t)b * CD + t] = v;       // final
        }
        __syncthreads();
        if (pass == 1) {
            if (t < 24) vsh2[t] = packh2(vsh[2*t], vsh[2*t+1]);
            __syncthreads();
        }
    }
#undef PASS_ROW
#undef REDUCE_H2
#undef SUM8
}

extern "C" void kernel_launch(void* const* d_in, const int* in_sizes, int n_in,
                              void* d_out, int out_size, void* d_ws, size_t ws_size,
                              hipStream_t stream) {
    (void)in_sizes; (void)n_in; (void)out_size;
    const float* x = (const float*)d_in[0];   // (B, N, 8) fp32
    const float* W = (const float*)d_in[1];   // (1, 3, N, 16, 8) fp32
    if (ws_size < (size_t)WSLOTS * 16) return;
    uint4* Wh = (uint4*)d_ws;

    hipLaunchKernelGGL(wcast, dim3(96), dim3(256), 0, stream, W, Wh);
    hipLaunchKernelGGL(fused, dim3(BB), dim3(TPB), 0, stream, x, Wh, (float*)d_out);
}

// Round 7
// 923.056 us; speedup vs baseline: 1.3448x; 1.3448x over previous
//
#include <hip/hip_runtime.h>
#include <hip/hip_fp16.h>

#define BB 2048
#define NN 1568
#define CD 48
#define G  8                      // batches per block = waves per block
#define WSLOTS 98304              // Wh uint4 slots (1.5 MB)
#define SFLTS (BB * CD)           // floats per s accumulator buffer

typedef _Float16 h2v __attribute__((ext_vector_type(2)));

// ---- scalar-safe half2 helpers
__device__ __forceinline__ unsigned packh2(float a, float b) {
    __half2 h = __floats2half2_rn(a, b);
    unsigned r; __builtin_memcpy(&r, &h, 4); return r;
}
__device__ __forceinline__ float2 uph2(unsigned v) {
    __half2 h; __builtin_memcpy(&h, &v, 4); return __half22float2(h);
}
__device__ __forceinline__ float fdot2u(unsigned a, unsigned b, float c) {
#if __has_builtin(__builtin_amdgcn_fdot2)
    h2v av, bv;
    __builtin_memcpy(&av, &a, 4); __builtin_memcpy(&bv, &b, 4);
    return __builtin_amdgcn_fdot2(av, bv, c, false);
#else
    const float2 fa = uph2(a), fb = uph2(b);
    return c + fa.x * fb.x + fa.y * fb.y;
#endif
}
__device__ __forceinline__ unsigned hadd2u(unsigned a, unsigned b) {
    __half2 ha, hb; __builtin_memcpy(&ha, &a, 4); __builtin_memcpy(&hb, &b, 4);
    __half2 r = __hadd2(ha, hb);
    unsigned q; __builtin_memcpy(&q, &r, 4); return q;
}
__device__ __forceinline__ unsigned hfma2u(unsigned a, unsigned b, unsigned c) {
    __half2 ha, hb, hc;
    __builtin_memcpy(&ha, &a, 4); __builtin_memcpy(&hb, &b, 4); __builtin_memcpy(&hc, &c, 4);
    __half2 r = __hfma2(ha, hb, hc);
    unsigned q; __builtin_memcpy(&q, &r, 4); return q;
}

// =================== K0: W fp32 -> fp16 swizzled, + zero s1..s3 ===================
// Wh slot layout: [ (c*4+g)*16 + d ][ ts ] (uint4 = 8 fp16 = all e of one d),
// covering n = g*512 + ts. rpass wave loads are fully coalesced.
__global__ __launch_bounds__(256)
void wcast(const float* __restrict__ W, uint4* __restrict__ Wh)
{
    const int id = blockIdx.x * 256 + threadIdx.x;   // 0..24575
    // zero the three 2048x48 f32 accumulators (re-zeroed every launch/replay)
    float* sz = (float*)(Wh + WSLOTS);
#pragma unroll
    for (int k = 0; k < 12; ++k) sz[id + k * 24576] = 0.f;

    const int ts = id & 511;
    const int r  = id >> 9;        // 0..47
    const int dq = r & 3;          // d quad (4 d per thread)
    const int ci = r >> 2;         // c*4+g, 0..11
    const int g  = ci & 3;
    const int c  = ci >> 2;
    const int n  = g * 512 + ts;
    uint4* dst = Wh + (size_t)ci * 8192 + dq * 4 * 512 + ts;
    if (n < NN) {
        const float* src = W + ((size_t)(c * NN + n)) * 128 + dq * 32;
#pragma unroll
        for (int dd = 0; dd < 4; ++dd) {
            const float4 f0 = *(const float4*)(src + dd * 8);
            const float4 f1 = *(const float4*)(src + dd * 8 + 4);
            uint4 q;
            q.x = packh2(f0.x, f0.y); q.y = packh2(f0.z, f0.w);
            q.z = packh2(f1.x, f1.y); q.w = packh2(f1.z, f1.w);
            dst[dd * 512] = q;
        }
    } else {
        const uint4 z = make_uint4(0u, 0u, 0u, 0u);
#pragma unroll
        for (int dd = 0; dd < 4; ++dd) dst[dd * 512] = z;
    }
}

// =================== rpass<P>: one streaming routing pass ===================
// Block = 512 thr = 8 waves; wave w owns batch b0+w (8 batches SHARE one
// W-chunk stream -> total W traffic 3x307 MB from L2, not 2.4 GB).
// u recomputed per row into 24 transient regs; no persistent u anywhere.
// P=0: acc += u (raw; 1/3 applied at squash). P=1: logits vs v1.
// P=2: logits vs v1+v2 (logits are linear in v). Wave-local shfl reduce,
// then 48 atomicAdds per wave into sout[b][48].
template<int P>
__global__ __launch_bounds__(512, 1)
void rpass(const float* __restrict__ x, const uint4* __restrict__ Wh,
           const float* __restrict__ s1in, const float* __restrict__ s2in,
           float* __restrict__ sout)
{
    __shared__ unsigned wv2[G][24];
    const int t    = threadIdx.x;
    const int w    = t >> 6;
    const int lane = t & 63;
    const int chunk = blockIdx.x / (BB / G);     // 0..2  (n-chunk of 512)
    const int bg    = blockIdx.x % (BB / G);
    const int b     = bg * G + w;

    unsigned wvr[24];
    if (P > 0) {
        if (t < G * CD) {
            const int bl = t / CD, cd = t % CD;
            float v;
            {
                const float a = s1in[(size_t)(bg * G + bl) * CD + cd] * (1.0f / 3.0f);
                float q = a * a;
                q += __shfl_xor(q, 1); q += __shfl_xor(q, 2);
                q += __shfl_xor(q, 4); q += __shfl_xor(q, 8);
                v = a * sqrtf(q) / (1.f + q);                  // v1
            }
            if (P == 2) {
                const float a = s2in[(size_t)(bg * G + bl) * CD + cd];
                float q = a * a;
                q += __shfl_xor(q, 1); q += __shfl_xor(q, 2);
                q += __shfl_xor(q, 4); q += __shfl_xor(q, 8);
                v += a * sqrtf(q) / (1.f + q);                 // + v2
            }
            const float vn = __shfl_xor(v, 1);
            if ((cd & 1) == 0) wv2[bl][cd >> 1] = packh2(v, vn);
        }
        __syncthreads();
#pragma unroll
        for (int j = 0; j < 24; ++j) wvr[j] = wv2[w][j];
    }

    unsigned acc[24];
#pragma unroll
    for (int j = 0; j < 24; ++j) acc[j] = 0u;

    const float* xb = x + (size_t)b * NN * 8;

#define DO_CC(C3, LL, GG, TS) { \
    const uint4* wp = Wh + (size_t)((C3) * 4 + (GG)) * 8192 + (TS); \
    _Pragma("unroll") \
    for (int dq = 0; dq < 4; ++dq) { \
        const uint4 w0 = wp[(dq * 4 + 0) * 512]; \
        const uint4 w1 = wp[(dq * 4 + 1) * 512]; \
        const uint4 w2 = wp[(dq * 4 + 2) * 512]; \
        const uint4 w3 = wp[(dq * 4 + 3) * 512]; \
        const float f0 = fdot2u(w0.x,xh0,fdot2u(w0.y,xh1,fdot2u(w0.z,xh2,fdot2u(w0.w,xh3,0.f)))); \
        const float f1 = fdot2u(w1.x,xh0,fdot2u(w1.y,xh1,fdot2u(w1.z,xh2,fdot2u(w1.w,xh3,0.f)))); \
        const float f2 = fdot2u(w2.x,xh0,fdot2u(w2.y,xh1,fdot2u(w2.z,xh2,fdot2u(w2.w,xh3,0.f)))); \
        const float f3 = fdot2u(w3.x,xh0,fdot2u(w3.y,xh1,fdot2u(w3.z,xh2,fdot2u(w3.w,xh3,0.f)))); \
        const unsigned pa = packh2(f0, f1); \
        const unsigned pb = packh2(f2, f3); \
        ur[(C3) * 8 + dq * 2]     = pa; \
        ur[(C3) * 8 + dq * 2 + 1] = pb; \
        if (P > 0) { \
            LL = fdot2u(pa, wvr[(C3) * 8 + dq * 2],     LL); \
            LL = fdot2u(pb, wvr[(C3) * 8 + dq * 2 + 1], LL); \
        } \
    } }

#define ROW_BODY(NROW, GG, TS) { \
    const float4 xa = __ldg((const float4*)(xb + (size_t)(NROW) * 8)); \
    const float4 xc = __ldg((const float4*)(xb + (size_t)(NROW) * 8 + 4)); \
    const unsigned xh0 = packh2(xa.x, xa.y), xh1 = packh2(xa.z, xa.w); \
    const unsigned xh2 = packh2(xc.x, xc.y), xh3 = packh2(xc.z, xc.w); \
    unsigned ur[24]; \
    float l0 = 0.f, l1 = 0.f, l2 = 0.f; \
    DO_CC(0, l0, GG, TS) DO_CC(1, l1, GG, TS) DO_CC(2, l2, GG, TS) \
    if (P == 0) { \
        (void)l0; (void)l1; (void)l2; \
        _Pragma("unroll") for (int j = 0; j < 24; ++j) acc[j] = hadd2u(acc[j], ur[j]); \
    } else { \
        const float e0 = __expf(l0), e1 = __expf(l1), e2 = __expf(l2); \
        const float inv = 1.f / (e0 + e1 + e2); \
        const unsigned c0h = packh2(e0 * inv, e0 * inv); \
        const unsigned c1h = packh2(e1 * inv, e1 * inv); \
        const unsigned c2h = packh2(e2 * inv, e2 * inv); \
        _Pragma("unroll") for (int j = 0; j < 8; ++j) { \
            acc[j]      = hfma2u(c0h, ur[j],      acc[j]); \
            acc[8 + j]  = hfma2u(c1h, ur[8 + j],  acc[8 + j]); \
            acc[16 + j] = hfma2u(c2h, ur[16 + j], acc[16 + j]); \
        } \
    } }

#pragma unroll 1
    for (int r = 0; r < 8; ++r) {
        const int n = chunk * 512 + r * 64 + lane;
        ROW_BODY(n, chunk, r * 64 + lane)
    }
    if (chunk == 2 && lane < 32) {        // tail rows 1536..1567 (g=3 in Wh)
        const int n = 1536 + lane;
        ROW_BODY(n, 3, lane)
    }
#undef ROW_BODY
#undef DO_CC

    // wave-local reduce (wave == batch) then one atomic per element
    float myv = 0.f;
#pragma unroll
    for (int j = 0; j < 24; ++j) {
        float2 g_ = uph2(acc[j]);
        g_.x += __shfl_xor(g_.x, 1);  g_.y += __shfl_xor(g_.y, 1);
        g_.x += __shfl_xor(g_.x, 2);  g_.y += __shfl_xor(g_.y, 2);
        g_.x += __shfl_xor(g_.x, 4);  g_.y += __shfl_xor(g_.y, 4);
        g_.x += __shfl_xor(g_.x, 8);  g_.y += __shfl_xor(g_.y, 8);
        g_.x += __shfl_xor(g_.x, 16); g_.y += __shfl_xor(g_.y, 16);
        g_.x += __shfl_xor(g_.x, 32); g_.y += __shfl_xor(g_.y, 32);
        if ((lane >> 1) == j) myv = (lane & 1) ? g_.y : g_.x;
    }
    if (lane < CD) atomicAdd(&sout[(size_t)b * CD + lane], myv);
}

// =================== F: out = squash(s3) ===================
__global__ __launch_bounds__(256)
void fsquash(const float* __restrict__ s3, float* __restrict__ out)
{
    const int idx = blockIdx.x * 256 + threadIdx.x;    // 0..98303
    const float s = s3[idx];
    float q = s * s;
    q += __shfl_xor(q, 1); q += __shfl_xor(q, 2);
    q += __shfl_xor(q, 4); q += __shfl_xor(q, 8);
    out[idx] = s * sqrtf(q) / (1.f + q);
}

extern "C" void kernel_launch(void* const* d_in, const int* in_sizes, int n_in,
                              void* d_out, int out_size, void* d_ws, size_t ws_size,
                              hipStream_t stream) {
    (void)in_sizes; (void)n_in; (void)out_size;
    const float* x = (const float*)d_in[0];   // (B, N, 8) fp32
    const float* W = (const float*)d_in[1];   // (1, 3, N, 16, 8) fp32
    if (ws_size < (size_t)WSLOTS * 16 + (size_t)3 * SFLTS * 4) return;
    uint4* Wh = (uint4*)d_ws;
    float* s1 = (float*)d_ws + (size_t)WSLOTS * 4;
    float* s2 = s1 + SFLTS;
    float* s3 = s2 + SFLTS;

    hipLaunchKernelGGL(wcast,    dim3(96),          dim3(256), 0, stream, W, Wh);
    hipLaunchKernelGGL(rpass<0>, dim3(3 * (BB / G)), dim3(512), 0, stream, x, Wh, s1, s2, s1);
    hipLaunchKernelGGL(rpass<1>, dim3(3 * (BB / G)), dim3(512), 0, stream, x, Wh, s1, s2, s2);
    hipLaunchKernelGGL(rpass<2>, dim3(3 * (BB / G)), dim3(512), 0, stream, x, Wh, s1, s2, s3);
    hipLaunchKernelGGL(fsquash,  dim3(384),         dim3(256), 0, stream, s3, (float*)d_out);
}

// Round 8
// 441.856 us; speedup vs baseline: 2.8094x; 2.0890x over previous
//
#include <hip/hip_runtime.h>
#include <hip/hip_fp16.h>

#define BB 2048
#define NN 1568
#define CD 48
#define G  8                      // batches per block = waves per block
#define WSLOTS 98304              // Wh uint4 slots (1.5 MB)
#define SFLTS (BB * CD)           // floats per s accumulator buffer

typedef _Float16 h2v __attribute__((ext_vector_type(2)));

// ---- scalar-safe half2 helpers
__device__ __forceinline__ unsigned packh2(float a, float b) {
    __half2 h = __floats2half2_rn(a, b);
    unsigned r; __builtin_memcpy(&r, &h, 4); return r;
}
__device__ __forceinline__ float2 uph2(unsigned v) {
    __half2 h; __builtin_memcpy(&h, &v, 4); return __half22float2(h);
}
__device__ __forceinline__ float fdot2u(unsigned a, unsigned b, float c) {
#if __has_builtin(__builtin_amdgcn_fdot2)
    h2v av, bv;
    __builtin_memcpy(&av, &a, 4); __builtin_memcpy(&bv, &b, 4);
    return __builtin_amdgcn_fdot2(av, bv, c, false);
#else
    const float2 fa = uph2(a), fb = uph2(b);
    return c + fa.x * fb.x + fa.y * fb.y;
#endif
}
__device__ __forceinline__ unsigned hadd2u(unsigned a, unsigned b) {
    __half2 ha, hb; __builtin_memcpy(&ha, &a, 4); __builtin_memcpy(&hb, &b, 4);
    __half2 r = __hadd2(ha, hb);
    unsigned q; __builtin_memcpy(&q, &r, 4); return q;
}
__device__ __forceinline__ unsigned hfma2u(unsigned a, unsigned b, unsigned c) {
    __half2 ha, hb, hc;
    __builtin_memcpy(&ha, &a, 4); __builtin_memcpy(&hb, &b, 4); __builtin_memcpy(&hc, &c, 4);
    __half2 r = __hfma2(ha, hb, hc);
    unsigned q; __builtin_memcpy(&q, &r, 4); return q;
}

// =================== K0: W fp32 -> fp16 swizzled, + zero s1..s3 ===================
__global__ __launch_bounds__(256)
void wcast(const float* __restrict__ W, uint4* __restrict__ Wh)
{
    const int id = blockIdx.x * 256 + threadIdx.x;   // 0..24575
    float* sz = (float*)(Wh + WSLOTS);
#pragma unroll
    for (int k = 0; k < 12; ++k) sz[id + k * 24576] = 0.f;

    const int ts = id & 511;
    const int r  = id >> 9;        // 0..47
    const int dq = r & 3;
    const int ci = r >> 2;         // c*4+g
    const int g  = ci & 3;
    const int c  = ci >> 2;
    const int n  = g * 512 + ts;
    uint4* dst = Wh + (size_t)ci * 8192 + dq * 4 * 512 + ts;
    if (n < NN) {
        const float* src = W + ((size_t)(c * NN + n)) * 128 + dq * 32;
#pragma unroll
        for (int dd = 0; dd < 4; ++dd) {
            const float4 f0 = *(const float4*)(src + dd * 8);
            const float4 f1 = *(const float4*)(src + dd * 8 + 4);
            uint4 q;
            q.x = packh2(f0.x, f0.y); q.y = packh2(f0.z, f0.w);
            q.z = packh2(f1.x, f1.y); q.w = packh2(f1.z, f1.w);
            dst[dd * 512] = q;
        }
    } else {
        const uint4 z = make_uint4(0u, 0u, 0u, 0u);
#pragma unroll
        for (int dd = 0; dd < 4; ++dd) dst[dd * 512] = z;
    }
}

// =================== rpass<P>: one streaming routing pass, LDS-staged W ===================
// Block = 512 thr = 8 waves; wave w owns batch bg*8+w. Per r-iter the block
// cooperatively stages the shared 48 KB W tile (48 d-streams x 64 n) into LDS
// ONCE; all 8 waves consume it via ds_read_b128. This removes the r7
// bottleneck (8 redundant per-wave global W streams, VMEM-latency-bound at
// ~330 us/pass) in favor of an LDS-bandwidth floor (~2.4 GB/pass @ ~85 B/cyc/CU).
// u recomputed per row into 24 transient regs; wave-local shfl reduce; 48
// atomicAdds per wave into sout[b][48].
template<int P>
__global__ __launch_bounds__(512, 1)
void rpass(const float* __restrict__ x, const uint4* __restrict__ Wh,
           const float* __restrict__ s1in, const float* __restrict__ s2in,
           float* __restrict__ sout)
{
    __shared__ uint4 wtile[3072];        // 48 KB: [s = c*16+d][ts0 0..63]
    __shared__ unsigned wv2s[G][24];
    const int t    = threadIdx.x;
    const int w    = t >> 6;
    const int lane = t & 63;
    const int chunk = blockIdx.x / (BB / G);     // 0..2 (n-chunk of 512)
    const int bg    = blockIdx.x % (BB / G);
    const int b     = bg * G + w;

    unsigned wvr[24];
    if (P > 0) {
        if (t < G * CD) {
            const int bl = t / CD, cd = t % CD;
            float v;
            {
                const float a = s1in[(size_t)(bg * G + bl) * CD + cd] * (1.0f / 3.0f);
                float q = a * a;
                q += __shfl_xor(q, 1); q += __shfl_xor(q, 2);
                q += __shfl_xor(q, 4); q += __shfl_xor(q, 8);
                v = a * sqrtf(q) / (1.f + q);                  // v1
            }
            if (P == 2) {
                const float a = s2in[(size_t)(bg * G + bl) * CD + cd];
                float q = a * a;
                q += __shfl_xor(q, 1); q += __shfl_xor(q, 2);
                q += __shfl_xor(q, 4); q += __shfl_xor(q, 8);
                v += a * sqrtf(q) / (1.f + q);                 // + v2
            }
            const float vn = __shfl_xor(v, 1);
            if ((cd & 1) == 0) wv2s[bl][cd >> 1] = packh2(v, vn);
        }
        __syncthreads();
#pragma unroll
        for (int j = 0; j < 24; ++j) wvr[j] = wv2s[w][j];
    }

    unsigned acc[24];
#pragma unroll
    for (int j = 0; j < 24; ++j) acc[j] = 0u;

    const float* xb = x + (size_t)b * NN * 8;

    // ---- per-class inner: W from LDS tile (WS) or global (WG expr) ----
#define DO_CL(C3, LL) { \
    _Pragma("unroll") \
    for (int dq = 0; dq < 4; ++dq) { \
        const uint4 w0 = wtile[((C3) * 16 + dq * 4 + 0) * 64 + lane]; \
        const uint4 w1 = wtile[((C3) * 16 + dq * 4 + 1) * 64 + lane]; \
        const uint4 w2 = wtile[((C3) * 16 + dq * 4 + 2) * 64 + lane]; \
        const uint4 w3 = wtile[((C3) * 16 + dq * 4 + 3) * 64 + lane]; \
        const float f0 = fdot2u(w0.x,xh0,fdot2u(w0.y,xh1,fdot2u(w0.z,xh2,fdot2u(w0.w,xh3,0.f)))); \
        const float f1 = fdot2u(w1.x,xh0,fdot2u(w1.y,xh1,fdot2u(w1.z,xh2,fdot2u(w1.w,xh3,0.f)))); \
        const float f2 = fdot2u(w2.x,xh0,fdot2u(w2.y,xh1,fdot2u(w2.z,xh2,fdot2u(w2.w,xh3,0.f)))); \
        const float f3 = fdot2u(w3.x,xh0,fdot2u(w3.y,xh1,fdot2u(w3.z,xh2,fdot2u(w3.w,xh3,0.f)))); \
        const unsigned pa = packh2(f0, f1); \
        const unsigned pb = packh2(f2, f3); \
        ur[(C3) * 8 + dq * 2]     = pa; \
        ur[(C3) * 8 + dq * 2 + 1] = pb; \
        if (P > 0) { \
            LL = fdot2u(pa, wvr[(C3) * 8 + dq * 2],     LL); \
            LL = fdot2u(pb, wvr[(C3) * 8 + dq * 2 + 1], LL); \
        } \
    } }

#define DO_CG(C3, LL, GG, TS) { \
    const uint4* wp = Wh + (size_t)((C3) * 4 + (GG)) * 8192 + (TS); \
    _Pragma("unroll") \
    for (int dq = 0; dq < 4; ++dq) { \
        const uint4 w0 = wp[(dq * 4 + 0) * 512]; \
        const uint4 w1 = wp[(dq * 4 + 1) * 512]; \
        const uint4 w2 = wp[(dq * 4 + 2) * 512]; \
        const uint4 w3 = wp[(dq * 4 + 3) * 512]; \
        const float f0 = fdot2u(w0.x,xh0,fdot2u(w0.y,xh1,fdot2u(w0.z,xh2,fdot2u(w0.w,xh3,0.f)))); \
        const float f1 = fdot2u(w1.x,xh0,fdot2u(w1.y,xh1,fdot2u(w1.z,xh2,fdot2u(w1.w,xh3,0.f)))); \
        const float f2 = fdot2u(w2.x,xh0,fdot2u(w2.y,xh1,fdot2u(w2.z,xh2,fdot2u(w2.w,xh3,0.f)))); \
        const float f3 = fdot2u(w3.x,xh0,fdot2u(w3.y,xh1,fdot2u(w3.z,xh2,fdot2u(w3.w,xh3,0.f)))); \
        const unsigned pa = packh2(f0, f1); \
        const unsigned pb = packh2(f2, f3); \
        ur[(C3) * 8 + dq * 2]     = pa; \
        ur[(C3) * 8 + dq * 2 + 1] = pb; \
        if (P > 0) { \
            LL = fdot2u(pa, wvr[(C3) * 8 + dq * 2],     LL); \
            LL = fdot2u(pb, wvr[(C3) * 8 + dq * 2 + 1], LL); \
        } \
    } }

#define ROW_TAIL(BODY0, BODY1, BODY2, NROW) { \
    const float4 xa = __ldg((const float4*)(xb + (size_t)(NROW) * 8)); \
    const float4 xc = __ldg((const float4*)(xb + (size_t)(NROW) * 8 + 4)); \
    const unsigned xh0 = packh2(xa.x, xa.y), xh1 = packh2(xa.z, xa.w); \
    const unsigned xh2 = packh2(xc.x, xc.y), xh3 = packh2(xc.z, xc.w); \
    unsigned ur[24]; \
    float l0 = 0.f, l1 = 0.f, l2 = 0.f; \
    BODY0 BODY1 BODY2 \
    if (P == 0) { \
        (void)l0; (void)l1; (void)l2; \
        _Pragma("unroll") for (int j = 0; j < 24; ++j) acc[j] = hadd2u(acc[j], ur[j]); \
    } else { \
        const float e0 = __expf(l0), e1 = __expf(l1), e2 = __expf(l2); \
        const float inv = 1.f / (e0 + e1 + e2); \
        const unsigned c0h = packh2(e0 * inv, e0 * inv); \
        const unsigned c1h = packh2(e1 * inv, e1 * inv); \
        const unsigned c2h = packh2(e2 * inv, e2 * inv); \
        _Pragma("unroll") for (int j = 0; j < 8; ++j) { \
            acc[j]      = hfma2u(c0h, ur[j],      acc[j]); \
            acc[8 + j]  = hfma2u(c1h, ur[8 + j],  acc[8 + j]); \
            acc[16 + j] = hfma2u(c2h, ur[16 + j], acc[16 + j]); \
        } \
    } }

#pragma unroll 1
    for (int r = 0; r < 8; ++r) {
        // ---- cooperative stage: 48 KB tile, 6 coalesced dwordx4 per thread ----
#pragma unroll
        for (int k = 0; k < 6; ++k) {
            const int q  = t + k * 512;          // 0..3071
            const int s  = q >> 6;               // d-stream 0..47 (c = s>>4, d = s&15)
            const int to = q & 63;
            wtile[q] = Wh[(size_t)((s >> 4) * 4 + chunk) * 8192 + (s & 15) * 512 + r * 64 + to];
        }
        __syncthreads();
        {
            const int n = chunk * 512 + r * 64 + lane;
            ROW_TAIL(DO_CL(0, l0), DO_CL(1, l1), DO_CL(2, l2), n)
        }
        __syncthreads();
    }
    if (chunk == 2 && lane < 32) {        // tail rows 1536..1567 (g=3), direct global
        const int n = 1536 + lane;
        ROW_TAIL(DO_CG(0, l0, 3, lane), DO_CG(1, l1, 3, lane), DO_CG(2, l2, 3, lane), n)
    }
#undef ROW_TAIL
#undef DO_CG
#undef DO_CL

    // wave-local reduce (wave == batch), one atomic per element
    float myv = 0.f;
#pragma unroll
    for (int j = 0; j < 24; ++j) {
        float2 g_ = uph2(acc[j]);
        g_.x += __shfl_xor(g_.x, 1);  g_.y += __shfl_xor(g_.y, 1);
        g_.x += __shfl_xor(g_.x, 2);  g_.y += __shfl_xor(g_.y, 2);
        g_.x += __shfl_xor(g_.x, 4);  g_.y += __shfl_xor(g_.y, 4);
        g_.x += __shfl_xor(g_.x, 8);  g_.y += __shfl_xor(g_.y, 8);
        g_.x += __shfl_xor(g_.x, 16); g_.y += __shfl_xor(g_.y, 16);
        g_.x += __shfl_xor(g_.x, 32); g_.y += __shfl_xor(g_.y, 32);
        if ((lane >> 1) == j) myv = (lane & 1) ? g_.y : g_.x;
    }
    if (lane < CD) atomicAdd(&sout[(size_t)b * CD + lane], myv);
}

// =================== F: out = squash(s3) ===================
__global__ __launch_bounds__(256)
void fsquash(const float* __restrict__ s3, float* __restrict__ out)
{
    const int idx = blockIdx.x * 256 + threadIdx.x;    // 0..98303
    const float s = s3[idx];
    float q = s * s;
    q += __shfl_xor(q, 1); q += __shfl_xor(q, 2);
    q += __shfl_xor(q, 4); q += __shfl_xor(q, 8);
    out[idx] = s * sqrtf(q) / (1.f + q);
}

extern "C" void kernel_launch(void* const* d_in, const int* in_sizes, int n_in,
                              void* d_out, int out_size, void* d_ws, size_t ws_size,
                              hipStream_t stream) {
    (void)in_sizes; (void)n_in; (void)out_size;
    const float* x = (const float*)d_in[0];   // (B, N, 8) fp32
    const float* W = (const float*)d_in[1];   // (1, 3, N, 16, 8) fp32
    if (ws_size < (size_t)WSLOTS * 16 + (size_t)3 * SFLTS * 4) return;
    uint4* Wh = (uint4*)d_ws;
    float* s1 = (float*)d_ws + (size_t)WSLOTS * 4;
    float* s2 = s1 + SFLTS;
    float* s3 = s2 + SFLTS;

    hipLaunchKernelGGL(wcast,    dim3(96),           dim3(256), 0, stream, W, Wh);
    hipLaunchKernelGGL(rpass<0>, dim3(3 * (BB / G)), dim3(512), 0, stream, x, Wh, s1, s2, s1);
    hipLaunchKernelGGL(rpass<1>, dim3(3 * (BB / G)), dim3(512), 0, stream, x, Wh, s1, s2, s2);
    hipLaunchKernelGGL(rpass<2>, dim3(3 * (BB / G)), dim3(512), 0, stream, x, Wh, s1, s2, s3);
    hipLaunchKernelGGL(fsquash,  dim3(384),          dim3(256), 0, stream, s3, (float*)d_out);
}